// Round 1
// baseline (630.035 us; speedup 1.0000x reference)
//
#include <hip/hip_runtime.h>
#include <stdint.h>

#define B_ 4
#define H_ 8
#define T_ 2048
#define C_ 1184
#define DK_ 148
#define DP_ 160
#define C3_ 3552

typedef __attribute__((ext_vector_type(8))) short s8v;
typedef __attribute__((ext_vector_type(4))) short s4v;
typedef __attribute__((ext_vector_type(4))) float f4v;

__device__ __forceinline__ unsigned short f2b(float f) {
  union { float f; unsigned u; } v; v.f = f;
  unsigned r = v.u + 0x7FFFu + ((v.u >> 16) & 1u);
  return (unsigned short)(r >> 16);
}

__global__ __launch_bounds__(256) void cvt4(const float* __restrict__ src,
                                            short* __restrict__ dst, int n4) {
  int i = blockIdx.x * 256 + threadIdx.x;
  if (i >= n4) return;
  float4 f = ((const float4*)src)[i];
  s4v o = { (short)f2b(f.x), (short)f2b(f.y), (short)f2b(f.z), (short)f2b(f.w) };
  ((s4v*)dst)[i] = o;
}

// C = A @ B^T (+bias). A: [M x 1184] bf16 row-major, B: [N x 1184] bf16 row-major.
// 128x128 tile, 4 waves of 64x64, mfma 16x16x32 bf16, BK=32, reg-staged LDS.
template <int EPI>
__global__ __launch_bounds__(256, 2) void gemm_bt(
    const short* __restrict__ A, const short* __restrict__ Bm,
    const float* __restrict__ bias,
    short* __restrict__ Qb, short* __restrict__ Kb, short* __restrict__ Vt,
    float* __restrict__ Out) {
  constexpr int K = C_;
  constexpr int NK = K / 32;  // 37
  __shared__ short As[128 * 32];
  __shared__ short Bs[128 * 32];
  const int tid = threadIdx.x;
  const int lane = tid & 63;
  const int wid = tid >> 6;
  const int lo = lane & 15, hi = lane >> 4;
  const int m0 = blockIdx.y * 128;
  const int n0 = blockIdx.x * 128;
  const int wr = wid >> 1, wc = wid & 1;

  // staging: granule g in [0,512), row=g>>2, seg=g&3; thread does g=tid, tid+256
  const int r0 = tid >> 2;
  const int sg = (tid & 3) * 8;
  const short* pa0 = A + (size_t)(m0 + r0) * K + sg;
  const short* pa1 = A + (size_t)(m0 + r0 + 64) * K + sg;
  const short* pb0 = Bm + (size_t)(n0 + r0) * K + sg;
  const short* pb1 = Bm + (size_t)(n0 + r0 + 64) * K + sg;

  s8v ra0 = *(const s8v*)pa0;
  s8v ra1 = *(const s8v*)pa1;
  s8v rb0 = *(const s8v*)pb0;
  s8v rb1 = *(const s8v*)pb1;

  f4v acc[4][4] = {};

  for (int ks = 0; ks < NK; ++ks) {
    __syncthreads();  // previous tile fully consumed
    *(s8v*)&As[tid * 8] = ra0;
    *(s8v*)&As[(tid + 256) * 8] = ra1;
    *(s8v*)&Bs[tid * 8] = rb0;
    *(s8v*)&Bs[(tid + 256) * 8] = rb1;
    if (ks + 1 < NK) {
      const int off = (ks + 1) * 32;
      ra0 = *(const s8v*)(pa0 + off);
      ra1 = *(const s8v*)(pa1 + off);
      rb0 = *(const s8v*)(pb0 + off);
      rb1 = *(const s8v*)(pb1 + off);
    }
    __syncthreads();
    s8v af[4], bf[4];
#pragma unroll
    for (int m = 0; m < 4; ++m)
      af[m] = *(const s8v*)&As[(wr * 64 + m * 16 + lo) * 32 + hi * 8];
#pragma unroll
    for (int n = 0; n < 4; ++n)
      bf[n] = *(const s8v*)&Bs[(wc * 64 + n * 16 + lo) * 32 + hi * 8];
#pragma unroll
    for (int m = 0; m < 4; ++m)
#pragma unroll
      for (int n = 0; n < 4; ++n)
        acc[m][n] = __builtin_amdgcn_mfma_f32_16x16x32_bf16(af[m], bf[n], acc[m][n], 0, 0, 0);
  }

#pragma unroll
  for (int n = 0; n < 4; ++n) {
    const int gn = n0 + wc * 64 + n * 16 + lo;
    if (EPI == 0) {
      if (gn < C3_) {
        const float bv = bias[gn];
        const int sel = gn / C_;
        const int r = gn - sel * C_;
        const int h = r / DK_;
        const int d = r - h * DK_;
#pragma unroll
        for (int m = 0; m < 4; ++m) {
#pragma unroll
          for (int j = 0; j < 4; ++j) {
            const int gm = m0 + wr * 64 + m * 16 + hi * 4 + j;
            const int b = gm >> 11, t = gm & 2047;
            const int bh = b * H_ + h;
            const short v = (short)f2b(acc[m][n][j] + bv);
            if (sel == 0)      Qb[((size_t)bh * T_ + t) * DP_ + d] = v;
            else if (sel == 1) Kb[((size_t)bh * T_ + t) * DP_ + d] = v;
            else               Vt[((size_t)bh * DP_ + d) * T_ + t] = v;
          }
        }
      }
    } else {
      if (gn < C_) {
        const float bv = bias[gn];
#pragma unroll
        for (int m = 0; m < 4; ++m)
#pragma unroll
          for (int j = 0; j < 4; ++j) {
            const int gm = m0 + wr * 64 + m * 16 + hi * 4 + j;
            Out[(size_t)gm * C_ + gn] = acc[m][n][j] + bv;
          }
      }
    }
  }
}

// Causal flash attention. Q,K: [B*H][T][160] bf16 (d 148..159 zeroed),
// Vt: [B*H][160][T] bf16. Y out: [B][T][1184] bf16.
// Block = 4 independent waves; wave owns 16 q rows; KV tiles of 32.
__global__ __launch_bounds__(256, 2) void attn(
    const short* __restrict__ Qb, const short* __restrict__ Kb,
    const short* __restrict__ Vt, short* __restrict__ Y) {
  constexpr float CSC = 0.11858886f;  // log2(e)/sqrt(148)
  __shared__ short Pl[4][16][40];     // per-wave P[q][kv], padded row (80B)
  const int tid = threadIdx.x;
  const int lane = tid & 63;
  const int wid = tid >> 6;
  const int lo = lane & 15, hi = lane >> 4;
  const int qt = blockIdx.x & 31;   // T/64 = 32 q-tiles
  const int bh = blockIdx.x >> 5;   // 0..31
  const int q0 = qt * 64 + wid * 16;
  const short* Qh = Qb + (size_t)bh * T_ * DP_;
  const short* Kh = Kb + (size_t)bh * T_ * DP_;
  const short* Vh = Vt + (size_t)bh * DP_ * T_;

  // Q B-fragments: lane holds q=q0+lo, d = c*32 + hi*8 .. +7
  s8v qf[5];
#pragma unroll
  for (int c = 0; c < 5; ++c)
    qf[c] = *(const s8v*)(Qh + (size_t)(q0 + lo) * DP_ + c * 32 + hi * 8);

  f4v acc[10] = {};  // Y^T chunks: rows d = c*16 + hi*4 + j, col q = lo
  float mrun = -INFINITY, lrun = 0.f;

  const int ntile = (q0 + 16 + 31) >> 5;
  for (int kt = 0; kt < ntile; ++kt) {
    const int kv0 = kt * 32;
    // S^T[kv][q] = K . Q^T  (two 16-kv sub-tiles)
    f4v s[2] = {};
#pragma unroll
    for (int t = 0; t < 2; ++t)
#pragma unroll
      for (int c = 0; c < 5; ++c) {
        s8v kf = *(const s8v*)(Kh + (size_t)(kv0 + t * 16 + lo) * DP_ + c * 32 + hi * 8);
        s[t] = __builtin_amdgcn_mfma_f32_16x16x32_bf16(kf, qf[c], s[t], 0, 0, 0);
      }
    // scale + causal mask; lane holds kv = kv0 + t*16 + hi*4 + j, q = q0 + lo
    float sv[2][4];
    float tm = -INFINITY;
    const bool need_mask = (kv0 + 31 > q0);
#pragma unroll
    for (int t = 0; t < 2; ++t)
#pragma unroll
      for (int j = 0; j < 4; ++j) {
        float v = s[t][j] * CSC;
        if (need_mask && (kv0 + t * 16 + hi * 4 + j > q0 + lo)) v = -INFINITY;
        sv[t][j] = v;
        tm = fmaxf(tm, v);
      }
    tm = fmaxf(tm, __shfl_xor(tm, 16));
    tm = fmaxf(tm, __shfl_xor(tm, 32));
    const float nm = fmaxf(mrun, tm);
    const float corr = exp2f(mrun - nm);
    float p[2][4];
    float ps = 0.f;
#pragma unroll
    for (int t = 0; t < 2; ++t)
#pragma unroll
      for (int j = 0; j < 4; ++j) {
        p[t][j] = exp2f(sv[t][j] - nm);
        ps += p[t][j];
      }
    ps += __shfl_xor(ps, 16);
    ps += __shfl_xor(ps, 32);
    lrun = lrun * corr + ps;
    mrun = nm;
#pragma unroll
    for (int c = 0; c < 10; ++c) acc[c] *= corr;

    // P -> LDS as Pl[q][kv] (bf16), then re-fragment as PV B-operand
#pragma unroll
    for (int t = 0; t < 2; ++t) {
      unsigned w0 = (unsigned)f2b(p[t][0]) | ((unsigned)f2b(p[t][1]) << 16);
      unsigned w1 = (unsigned)f2b(p[t][2]) | ((unsigned)f2b(p[t][3]) << 16);
      *(unsigned*)&Pl[wid][lo][t * 16 + hi * 4] = w0;
      *(unsigned*)&Pl[wid][lo][t * 16 + hi * 4 + 2] = w1;
    }
    s8v pf = *(const s8v*)&Pl[wid][lo][hi * 8];
    // Y^T += V^T . P^T ; A-frag: rows d = c*16+lo, k = kv = hi*8..+7 (contiguous in Vt)
#pragma unroll
    for (int c = 0; c < 10; ++c) {
      s8v vf = *(const s8v*)(Vh + (size_t)(c * 16 + lo) * T_ + kv0 + hi * 8);
      acc[c] = __builtin_amdgcn_mfma_f32_16x16x32_bf16(vf, pf, acc[c], 0, 0, 0);
    }
  }

  // epilogue: Y[b][t][h*148 + d] (bf16), divide by l, skip pad d>=148
  const float inv = 1.0f / lrun;
  const int b = bh >> 3, h = bh & 7;
  const int trow = q0 + lo;
  const size_t ybase = ((size_t)(b * T_ + trow)) * C_ + h * DK_;
#pragma unroll
  for (int c = 0; c < 10; ++c) {
    const int d0 = c * 16 + hi * 4;
    if (d0 + 3 < DK_) {
      s4v o = { (short)f2b(acc[c][0] * inv), (short)f2b(acc[c][1] * inv),
                (short)f2b(acc[c][2] * inv), (short)f2b(acc[c][3] * inv) };
      *(s4v*)(Y + ybase + d0) = o;
    }
  }
}

extern "C" void kernel_launch(void* const* d_in, const int* in_sizes, int n_in,
                              void* d_out, int out_size, void* d_ws, size_t ws_size,
                              hipStream_t stream) {
  const float* x  = (const float*)d_in[0];
  const float* wA = (const float*)d_in[1];
  const float* bA = (const float*)d_in[2];
  const float* wP = (const float*)d_in[3];
  const float* bP = (const float*)d_in[4];
  float* out = (float*)d_out;

  short* ws  = (short*)d_ws;
  short* xb  = ws;                  // [8192][1184] bf16; later reused as Y
  short* wab = xb + 9699328;        // [3584][1184] (rows 3552.. garbage, unused)
  short* wpb = wab + 4243456;       // [1280][1184] (rows 1184.. garbage, unused)
  short* Qb  = wpb + 1515520;       // [32][2048][160]
  short* Kb  = Qb + 10485760;       // [32][2048][160]
  short* Vt  = Kb + 10485760;       // [32][160][2048]

  cvt4<<<(9699328 / 4 + 255) / 256, 256, 0, stream>>>(x, xb, 9699328 / 4);
  cvt4<<<(4205568 / 4 + 255) / 256, 256, 0, stream>>>(wA, wab, 4205568 / 4);
  cvt4<<<(1401856 / 4 + 255) / 256, 256, 0, stream>>>(wP, wpb, 1401856 / 4);
  // zero Q,K so the d=148..159 contraction pad is exactly 0
  hipMemsetAsync(Qb, 0, (size_t)10485760 * 2, stream);
  hipMemsetAsync(Kb, 0, (size_t)10485760 * 2, stream);

  gemm_bt<0><<<dim3(28, 64), 256, 0, stream>>>(xb, wab, bA, Qb, Kb, Vt, nullptr);
  attn<<<1024, 256, 0, stream>>>(Qb, Kb, Vt, xb);  // Y aliases xb (dead)
  gemm_bt<1><<<dim3(10, 64), 256, 0, stream>>>(xb, wpb, bP, nullptr, nullptr, nullptr, out);
}

// Round 2
// 431.492 us; speedup vs baseline: 1.4601x; 1.4601x over previous
//
#include <hip/hip_runtime.h>
#include <stdint.h>

#define B_ 4
#define H_ 8
#define T_ 2048
#define C_ 1184
#define DK_ 148
#define DP_ 160
#define C3_ 3552

typedef __attribute__((ext_vector_type(8))) short s8v;
typedef __attribute__((ext_vector_type(4))) short s4v;
typedef __attribute__((ext_vector_type(4))) float f4v;

#define CSC 0.11858886f  /* log2(e)/sqrt(148) */

__device__ __forceinline__ unsigned short f2b(float f) {
  union { float f; unsigned u; } v; v.f = f;
  unsigned r = v.u + 0x7FFFu + ((v.u >> 16) & 1u);
  return (unsigned short)(r >> 16);
}

__device__ __forceinline__ void gld16(const void* g, void* l) {
  __builtin_amdgcn_global_load_lds(
      (const __attribute__((address_space(1))) void*)g,
      (__attribute__((address_space(3))) void*)l, 16, 0, 0);
}

__global__ __launch_bounds__(256) void cvt4(const float* __restrict__ src,
                                            short* __restrict__ dst, int n4) {
  int i = blockIdx.x * 256 + threadIdx.x;
  if (i >= n4) return;
  float4 f = ((const float4*)src)[i];
  s4v o = { (short)f2b(f.x), (short)f2b(f.y), (short)f2b(f.z), (short)f2b(f.w) };
  ((s4v*)dst)[i] = o;
}

// C = A @ B^T (+bias). A: [M x 1184] bf16, B: [N x 1184] bf16 row-major.
// 128x128 tile, 4 waves of 64x64, mfma 16x16x32 bf16, BK=32,
// global_load_lds(16B) staging, double-buffered 2-phase prefetch.
template <int EPI>
__global__ __launch_bounds__(256, 2) void gemm_bt(
    const short* __restrict__ A, const short* __restrict__ Bm,
    const float* __restrict__ bias,
    short* __restrict__ Qb, short* __restrict__ Kb, short* __restrict__ Vt,
    float* __restrict__ Out) {
  constexpr int K = C_;
  constexpr int NK = K / 32;  // 37
  __shared__ short As[2][128 * 32];
  __shared__ short Bs[2][128 * 32];
  const int tid = threadIdx.x;
  const int lane = tid & 63;
  const int wid = tid >> 6;
  const int lo = lane & 15, hi = lane >> 4;
  const int m0 = blockIdx.y * 128;
  const int n0 = blockIdx.x * 128;
  const int wr = wid >> 1, wc = wid & 1;

  // staging granule: row = tid>>2, 8-short segment = tid&3; LDS dest linear in tid
  const int r0 = tid >> 2;
  const int sg = (tid & 3) * 8;
  const short* pa0 = A + (size_t)(m0 + r0) * K + sg;
  const short* pa1 = A + (size_t)(m0 + r0 + 64) * K + sg;
  const short* pb0 = Bm + (size_t)(n0 + r0) * K + sg;
  const short* pb1 = Bm + (size_t)(n0 + r0 + 64) * K + sg;

  f4v acc[4][4] = {};

#define STAGE(kk, buf)                                \
  do {                                                \
    const int _o = (kk) * 32;                         \
    gld16(pa0 + _o, &As[(buf)][tid * 8]);             \
    gld16(pa1 + _o, &As[(buf)][(tid + 256) * 8]);     \
    gld16(pb0 + _o, &Bs[(buf)][tid * 8]);             \
    gld16(pb1 + _o, &Bs[(buf)][(tid + 256) * 8]);     \
  } while (0)

  STAGE(0, 0);
  int cur = 0;
  for (int ks = 0; ks < NK; ++ks) {
    __syncthreads();  // drains vmcnt -> buf[cur] ready; buf[cur^1] consumed
    if (ks + 1 < NK) STAGE(ks + 1, cur ^ 1);
    const short* Ab = As[cur];
    const short* Bb = Bs[cur];
    s8v af[4], bf[4];
#pragma unroll
    for (int m = 0; m < 4; ++m)
      af[m] = *(const s8v*)&Ab[(wr * 64 + m * 16 + lo) * 32 + hi * 8];
#pragma unroll
    for (int n = 0; n < 4; ++n)
      bf[n] = *(const s8v*)&Bb[(wc * 64 + n * 16 + lo) * 32 + hi * 8];
#pragma unroll
    for (int m = 0; m < 4; ++m)
#pragma unroll
      for (int n = 0; n < 4; ++n)
        acc[m][n] = __builtin_amdgcn_mfma_f32_16x16x32_bf16(af[m], bf[n], acc[m][n], 0, 0, 0);
    cur ^= 1;
  }
#undef STAGE

#pragma unroll
  for (int n = 0; n < 4; ++n) {
    const int gn = n0 + wc * 64 + n * 16 + lo;
    if (EPI == 0) {
      if (gn < C3_) {
        const float bv = bias[gn];
        const int sel = gn / C_;
        const int r = gn - sel * C_;
        const int h = r / DK_;
        const int d = r - h * DK_;
#pragma unroll
        for (int m = 0; m < 4; ++m) {
#pragma unroll
          for (int j = 0; j < 4; ++j) {
            const int gm = m0 + wr * 64 + m * 16 + hi * 4 + j;
            const int b = gm >> 11, t = gm & 2047;
            const int bh = b * H_ + h;
            const float fv = acc[m][n][j] + bv;
            if (sel == 0)      Qb[((size_t)bh * T_ + t) * DP_ + d] = (short)f2b(fv * CSC);
            else if (sel == 1) Kb[((size_t)bh * T_ + t) * DP_ + d] = (short)f2b(fv);
            else               Vt[((size_t)bh * DP_ + d) * T_ + t] = (short)f2b(fv);
          }
        }
      }
    } else {
      if (gn < C_) {
        const float bv = bias[gn];
#pragma unroll
        for (int m = 0; m < 4; ++m)
#pragma unroll
          for (int j = 0; j < 4; ++j) {
            const int gm = m0 + wr * 64 + m * 16 + hi * 4 + j;
            Out[(size_t)gm * C_ + gn] = acc[m][n][j] + bv;
          }
      }
    }
  }
}

// Causal flash attention. Q (pre-scaled by log2e/sqrt(dk)), K: [32][2048][160] bf16
// (d=148..159 zeroed), Vt: [32][160][2048] bf16. Y: [4][2048][1184] bf16.
// Block = 4 independent waves; wave owns 32 q rows; kv tiles of 64; K/V direct
// from global (L2/L3 resident); P re-fragmented via per-wave LDS.
__global__ __launch_bounds__(256, 2) void attn(
    const short* __restrict__ Qb, const short* __restrict__ Kb,
    const short* __restrict__ Vt, short* __restrict__ Y) {
  __shared__ short Pl[4][2][16][72];  // [wave][qsub][q][kv(64)+pad]
  const int tid = threadIdx.x;
  const int lane = tid & 63;
  const int wid = tid >> 6;
  const int lo = lane & 15, hi = lane >> 4;
  // work-balance: block i and i+256 get complementary q-blocks (qb+qb'=15)
  const int raw = blockIdx.x;
  int bh, qb;
  if (raw < 256) { bh = raw >> 4; qb = raw & 15; }
  else { const int r = raw - 256; bh = 16 + (r >> 4); qb = 15 - (r & 15); }
  const int q0 = qb * 128 + wid * 32;
  const short* Qh = Qb + (size_t)bh * T_ * DP_;
  const short* Kh = Kb + (size_t)bh * T_ * DP_;
  const short* Vh = Vt + (size_t)bh * DP_ * T_;

  // Q B-fragments: lane holds q = q0 + u*16 + lo, d = c*32 + hi*8 .. +7
  s8v qf[2][5];
#pragma unroll
  for (int u = 0; u < 2; ++u)
#pragma unroll
    for (int c = 0; c < 5; ++c)
      qf[u][c] = *(const s8v*)(Qh + (size_t)(q0 + u * 16 + lo) * DP_ + c * 32 + hi * 8);

  f4v acc[10][2] = {};  // Y^T: row d = c*16 + hi*4 + j, col q = lo (per qsub)
  float mrun[2] = { -INFINITY, -INFINITY };
  float lrun[2] = { 0.f, 0.f };

  const int nt = (q0 + 32 + 63) >> 6;
  for (int kt = 0; kt < nt; ++kt) {
    const int kv0 = kt * 64;
    // S^T[kv][q] = K . Q^T over 4 kv sub-tiles of 16
    f4v s[2][4] = {};
#pragma unroll
    for (int t = 0; t < 4; ++t) {
      s8v kf[5];
#pragma unroll
      for (int c = 0; c < 5; ++c)
        kf[c] = *(const s8v*)(Kh + (size_t)(kv0 + t * 16 + lo) * DP_ + c * 32 + hi * 8);
#pragma unroll
      for (int c = 0; c < 5; ++c) {
        s[0][t] = __builtin_amdgcn_mfma_f32_16x16x32_bf16(kf[c], qf[0][c], s[0][t], 0, 0, 0);
        s[1][t] = __builtin_amdgcn_mfma_f32_16x16x32_bf16(kf[c], qf[1][c], s[1][t], 0, 0, 0);
      }
    }
    // causal mask only on the diagonal tile (wave-uniform branch)
    if (kv0 + 63 > q0) {
#pragma unroll
      for (int u = 0; u < 2; ++u) {
        const int qrow = q0 + u * 16 + lo;
#pragma unroll
        for (int t = 0; t < 4; ++t)
#pragma unroll
          for (int j = 0; j < 4; ++j)
            if (kv0 + t * 16 + hi * 4 + j > qrow) s[u][t][j] = -INFINITY;
      }
    }
    // online softmax (exp2 domain; Q pre-scaled). lane holds kv=kv0+t*16+hi*4+j, q per lo
#pragma unroll
    for (int u = 0; u < 2; ++u) {
      float tm = -INFINITY;
#pragma unroll
      for (int t = 0; t < 4; ++t)
#pragma unroll
        for (int j = 0; j < 4; ++j) tm = fmaxf(tm, s[u][t][j]);
      tm = fmaxf(tm, __shfl_xor(tm, 16));
      tm = fmaxf(tm, __shfl_xor(tm, 32));
      const float nm = fmaxf(mrun[u], tm);
      const float corr = exp2f(mrun[u] - nm);
      mrun[u] = nm;
      float ps = 0.f;
      float p[4][4];
#pragma unroll
      for (int t = 0; t < 4; ++t)
#pragma unroll
        for (int j = 0; j < 4; ++j) { p[t][j] = exp2f(s[u][t][j] - nm); ps += p[t][j]; }
      ps += __shfl_xor(ps, 16);
      ps += __shfl_xor(ps, 32);
      lrun[u] = lrun[u] * corr + ps;
#pragma unroll
      for (int c = 0; c < 10; ++c) acc[c][u] *= corr;
#pragma unroll
      for (int t = 0; t < 4; ++t) {
        s4v w = { (short)f2b(p[t][0]), (short)f2b(p[t][1]),
                  (short)f2b(p[t][2]), (short)f2b(p[t][3]) };
        *(s4v*)&Pl[wid][u][lo][t * 16 + hi * 4] = w;
      }
    }
    // re-fragment P as PV B-operand: lane holds q=lo, kv = w*32 + hi*8 .. +7
    s8v pf[2][2];
#pragma unroll
    for (int u = 0; u < 2; ++u)
#pragma unroll
      for (int w = 0; w < 2; ++w)
        pf[u][w] = *(const s8v*)&Pl[wid][u][lo][w * 32 + hi * 8];
    // Y^T += V^T . P^T ; vf: row d = c*16+lo, kv = kv0 + w*32 + hi*8 (contig in Vt)
#pragma unroll
    for (int c = 0; c < 10; ++c)
#pragma unroll
      for (int w = 0; w < 2; ++w) {
        s8v vf = *(const s8v*)(Vh + (size_t)(c * 16 + lo) * T_ + kv0 + w * 32 + hi * 8);
        acc[c][0] = __builtin_amdgcn_mfma_f32_16x16x32_bf16(vf, pf[0][w], acc[c][0], 0, 0, 0);
        acc[c][1] = __builtin_amdgcn_mfma_f32_16x16x32_bf16(vf, pf[1][w], acc[c][1], 0, 0, 0);
      }
  }

  // epilogue: Y[b][t][h*148 + d] bf16, divide by l, skip pad d >= 148
  const int b = bh >> 3, h = bh & 7;
#pragma unroll
  for (int u = 0; u < 2; ++u) {
    const float inv = 1.0f / lrun[u];
    const int trow = q0 + u * 16 + lo;
    const size_t ybase = ((size_t)(b * T_ + trow)) * C_ + h * DK_;
#pragma unroll
    for (int c = 0; c < 10; ++c) {
      const int d0 = c * 16 + hi * 4;
      if (d0 + 3 < DK_) {
        s4v o = { (short)f2b(acc[c][u][0] * inv), (short)f2b(acc[c][u][1] * inv),
                  (short)f2b(acc[c][u][2] * inv), (short)f2b(acc[c][u][3] * inv) };
        *(s4v*)(Y + ybase + d0) = o;
      }
    }
  }
}

extern "C" void kernel_launch(void* const* d_in, const int* in_sizes, int n_in,
                              void* d_out, int out_size, void* d_ws, size_t ws_size,
                              hipStream_t stream) {
  const float* x  = (const float*)d_in[0];
  const float* wA = (const float*)d_in[1];
  const float* bA = (const float*)d_in[2];
  const float* wP = (const float*)d_in[3];
  const float* bP = (const float*)d_in[4];
  float* out = (float*)d_out;

  short* ws  = (short*)d_ws;
  short* xb  = ws;                  // [8192][1184] bf16; later reused as Y
  short* wab = xb + 9699328;        // [3584][1184] (rows 3552.. garbage, unused)
  short* wpb = wab + 4243456;       // [1280][1184] (rows 1184.. garbage, unused)
  short* Qb  = wpb + 1515520;       // [32][2048][160]
  short* Kb  = Qb + 10485760;       // [32][2048][160]
  short* Vt  = Kb + 10485760;       // [32][160][2048]

  cvt4<<<(9699328 / 4 + 255) / 256, 256, 0, stream>>>(x, xb, 9699328 / 4);
  cvt4<<<(4205568 / 4 + 255) / 256, 256, 0, stream>>>(wA, wab, 4205568 / 4);
  cvt4<<<(1401856 / 4 + 255) / 256, 256, 0, stream>>>(wP, wpb, 1401856 / 4);
  // zero Q,K so the d=148..159 contraction pad is exactly 0
  hipMemsetAsync(Qb, 0, (size_t)10485760 * 2, stream);
  hipMemsetAsync(Kb, 0, (size_t)10485760 * 2, stream);

  gemm_bt<0><<<dim3(28, 64), 256, 0, stream>>>(xb, wab, bA, Qb, Kb, Vt, nullptr);
  attn<<<512, 256, 0, stream>>>(Qb, Kb, Vt, xb);  // Y aliases xb (dead)
  gemm_bt<1><<<dim3(10, 64), 256, 0, stream>>>(xb, wpb, bP, nullptr, nullptr, nullptr, out);
}

// Round 3
// 319.360 us; speedup vs baseline: 1.9728x; 1.3511x over previous
//
#include <hip/hip_runtime.h>
#include <stdint.h>

#define B_ 4
#define H_ 8
#define T_ 2048
#define C_ 1184
#define DK_ 148
#define DP_ 160
#define C3_ 3552

typedef __attribute__((ext_vector_type(8))) short s8v;
typedef __attribute__((ext_vector_type(4))) short s4v;
typedef __attribute__((ext_vector_type(4))) float f4v;

#define CSC 0.11858886f  /* log2(e)/sqrt(148) */

__device__ __forceinline__ unsigned short f2b(float f) {
  union { float f; unsigned u; } v; v.f = f;
  unsigned r = v.u + 0x7FFFu + ((v.u >> 16) & 1u);
  return (unsigned short)(r >> 16);
}

__device__ __forceinline__ void gld16(const void* g, void* l) {
  __builtin_amdgcn_global_load_lds(
      (const __attribute__((address_space(1))) void*)g,
      (__attribute__((address_space(3))) void*)l, 16, 0, 0);
}

__global__ __launch_bounds__(256) void cvt4(const float* __restrict__ src,
                                            short* __restrict__ dst, int n4) {
  int i = blockIdx.x * 256 + threadIdx.x;
  if (i >= n4) return;
  float4 f = ((const float4*)src)[i];
  s4v o = { (short)f2b(f.x), (short)f2b(f.y), (short)f2b(f.z), (short)f2b(f.w) };
  ((s4v*)dst)[i] = o;
}

// C = A @ B^T (+bias). 128x128 tile, 4 waves, mfma 16x16x32 bf16, BK=32,
// global_load_lds(16B) staging, double-buffered. XCD-chunked 1D grid:
// xcd = bid&7 owns m-band [xcd*8, xcd*8+8) tiles, iterates all NT n-tiles.
template <int EPI, int NT>
__global__ __launch_bounds__(256, 2) void gemm_bt(
    const short* __restrict__ A, const short* __restrict__ Bm,
    const float* __restrict__ bias,
    short* __restrict__ Qb, short* __restrict__ Kb, short* __restrict__ Vt,
    float* __restrict__ Out) {
  constexpr int K = C_;
  constexpr int NK = K / 32;  // 37
  __shared__ short As[2][128 * 32];
  __shared__ short Bs[2][128 * 32];
  const int tid = threadIdx.x;
  const int lane = tid & 63;
  const int wid = tid >> 6;
  const int lo = lane & 15, hi = lane >> 4;
  const int bid = blockIdx.x;
  const int xcd = bid & 7;
  const int kk = bid >> 3;
  const int m0 = (xcd * 8 + kk / NT) * 128;
  const int n0 = (kk % NT) * 128;
  const int wr = wid >> 1, wc = wid & 1;

  const int r0 = tid >> 2;
  const int sg = (tid & 3) * 8;
  const short* pa0 = A + (size_t)(m0 + r0) * K + sg;
  const short* pa1 = A + (size_t)(m0 + r0 + 64) * K + sg;
  const short* pb0 = Bm + (size_t)(n0 + r0) * K + sg;
  const short* pb1 = Bm + (size_t)(n0 + r0 + 64) * K + sg;

  f4v acc[4][4] = {};

#define STAGE(kk_, buf)                               \
  do {                                                \
    const int _o = (kk_) * 32;                        \
    gld16(pa0 + _o, &As[(buf)][tid * 8]);             \
    gld16(pa1 + _o, &As[(buf)][(tid + 256) * 8]);     \
    gld16(pb0 + _o, &Bs[(buf)][tid * 8]);             \
    gld16(pb1 + _o, &Bs[(buf)][(tid + 256) * 8]);     \
  } while (0)

  STAGE(0, 0);
  int cur = 0;
  for (int ks = 0; ks < NK; ++ks) {
    __syncthreads();  // drains vmcnt -> buf[cur] ready; buf[cur^1] consumed
    if (ks + 1 < NK) STAGE(ks + 1, cur ^ 1);
    const short* Ab = As[cur];
    const short* Bb = Bs[cur];
    s8v af[4], bf[4];
#pragma unroll
    for (int m = 0; m < 4; ++m)
      af[m] = *(const s8v*)&Ab[(wr * 64 + m * 16 + lo) * 32 + hi * 8];
#pragma unroll
    for (int n = 0; n < 4; ++n)
      bf[n] = *(const s8v*)&Bb[(wc * 64 + n * 16 + lo) * 32 + hi * 8];
#pragma unroll
    for (int m = 0; m < 4; ++m)
#pragma unroll
      for (int n = 0; n < 4; ++n)
        acc[m][n] = __builtin_amdgcn_mfma_f32_16x16x32_bf16(af[m], bf[n], acc[m][n], 0, 0, 0);
    cur ^= 1;
  }
#undef STAGE

#pragma unroll
  for (int n = 0; n < 4; ++n) {
    const int gn = n0 + wc * 64 + n * 16 + lo;
    if (EPI == 0) {
      if (gn < C3_) {
        const float bv = bias[gn];
        const int sel = gn / C_;
        const int r = gn - sel * C_;
        const int h = r / DK_;
        const int d = r - h * DK_;
#pragma unroll
        for (int m = 0; m < 4; ++m) {
          const int t0 = m0 + wr * 64 + m * 16 + hi * 4;
          const int b = t0 >> 11, tt = t0 & 2047;
          const int bh = b * H_ + h;
          if (sel == 2) {  // V^T: 4 consecutive t for fixed d -> vector store
            s4v o = { (short)f2b(acc[m][n][0] + bv), (short)f2b(acc[m][n][1] + bv),
                      (short)f2b(acc[m][n][2] + bv), (short)f2b(acc[m][n][3] + bv) };
            *(s4v*)&Vt[((size_t)bh * DP_ + d) * T_ + tt] = o;
          } else {
#pragma unroll
            for (int j = 0; j < 4; ++j) {
              const short v = (sel == 0) ? (short)f2b((acc[m][n][j] + bv) * CSC)
                                         : (short)f2b(acc[m][n][j] + bv);
              if (sel == 0) Qb[((size_t)bh * T_ + tt + j) * DP_ + d] = v;
              else          Kb[((size_t)bh * T_ + tt + j) * DP_ + d] = v;
            }
          }
        }
      }
    } else {
      if (gn < C_) {
        const float bv = bias[gn];
#pragma unroll
        for (int m = 0; m < 4; ++m)
#pragma unroll
          for (int j = 0; j < 4; ++j) {
            const int gm = m0 + wr * 64 + m * 16 + hi * 4 + j;
            Out[(size_t)gm * C_ + gn] = acc[m][n][j] + bv;
          }
      }
    }
  }
}

// Causal flash attention, block-shared LDS-staged K/V tiles.
// Q (pre-scaled), K: [32][2048][160] bf16 (d pad zeroed), Vt: [32][160][2048].
// Block = 4 waves x 32 q rows (128 q rows); kv tiles of 64, double-buffered
// global_load_lds with source-side XOR swizzle; one barrier per tile.
__global__ __launch_bounds__(256, 1) void attn(
    const short* __restrict__ Qb, const short* __restrict__ Kb,
    const short* __restrict__ Vt, short* __restrict__ Y) {
  __shared__ short Ks[2][10240];  // [5 c][64 r][4 granules], granule-XOR w^((r>>1)&3)
  __shared__ short Vs[2][10240];  // [160 d][8 granules], granule-XOR w^(d&7)
  __shared__ short Pl[4][2][16][72];
  const int tid = threadIdx.x;
  const int lane = tid & 63;
  const int wid = tid >> 6;
  const int lo = lane & 15, hi = lane >> 4;
  // XCD-aware balanced remap: xcd owns 4 bh; qb paired with 15-qb for backfill
  const int s = blockIdx.x;
  const int xcd = s & 7;
  const int k = s >> 3;
  int qb, bsub;
  if (k < 32) { bsub = k >> 4; qb = k & 15; }
  else { bsub = 2 + ((k - 32) >> 4); qb = 15 - (k & 15); }
  const int bh = xcd * 4 + bsub;
  const int q0 = qb * 128 + wid * 32;
  const short* Qh = Qb + (size_t)bh * T_ * DP_;
  const short* Kh = Kb + (size_t)bh * T_ * DP_;
  const short* Vh = Vt + (size_t)bh * DP_ * T_;

  // Q B-fragments: lane holds q = q0 + u*16 + lo, d = c*32 + hi*8 .. +7
  s8v qf[2][5];
#pragma unroll
  for (int u = 0; u < 2; ++u)
#pragma unroll
    for (int c = 0; c < 5; ++c)
      qf[u][c] = *(const s8v*)(Qh + (size_t)(q0 + u * 16 + lo) * DP_ + c * 32 + hi * 8);

  f4v acc[10][2] = {};
  float mrun[2] = { -INFINITY, -INFINITY };
  float lrun[2] = { 0.f, 0.f };
  const int swzk = hi ^ ((lo >> 1) & 3);
  const int nt = 2 * (qb + 1);  // uniform across the block's 4 waves

#define STAGEKV(kt_, buf_)                                                   \
  do {                                                                       \
    const size_t kvo_ = (size_t)(kt_) * 64;                                  \
    _Pragma("unroll")                                                        \
    for (int i_ = 0; i_ < 5; ++i_) {                                         \
      const int g_ = tid + i_ * 256;                                         \
      const int c_ = g_ >> 8, re_ = g_ & 255, r_ = re_ >> 2, wz_ = re_ & 3;  \
      const int w_ = wz_ ^ ((r_ >> 1) & 3);                                  \
      gld16(Kh + (kvo_ + r_) * DP_ + c_ * 32 + w_ * 8, &Ks[buf_][g_ * 8]);   \
      const int d_ = g_ >> 3, vz_ = g_ & 7;                                  \
      const int v_ = vz_ ^ (d_ & 7);                                         \
      gld16(Vh + (size_t)d_ * T_ + kvo_ + v_ * 8, &Vs[buf_][g_ * 8]);        \
    }                                                                        \
  } while (0)

  STAGEKV(0, 0);
  int cur = 0;
  for (int kt = 0; kt < nt; ++kt) {
    __syncthreads();  // stage of buf[cur] drained; buf[cur^1] free
    if (kt + 1 < nt) STAGEKV(kt + 1, cur ^ 1);
    const int kv0 = kt * 64;
    if (kv0 <= q0 + 31) {  // wave-uniform: skip fully-masked tail tiles
      const short* Kc = Ks[cur];
      const short* Vc = Vs[cur];
      // S^T[kv][q] = K . Q^T over 4 kv sub-tiles of 16
      f4v sc[2][4] = {};
#pragma unroll
      for (int t = 0; t < 4; ++t) {
        s8v kf[5];
#pragma unroll
        for (int c = 0; c < 5; ++c)
          kf[c] = *(const s8v*)&Kc[(c * 256 + (t * 16 + lo) * 4 + swzk) * 8];
#pragma unroll
        for (int c = 0; c < 5; ++c) {
          sc[0][t] = __builtin_amdgcn_mfma_f32_16x16x32_bf16(kf[c], qf[0][c], sc[0][t], 0, 0, 0);
          sc[1][t] = __builtin_amdgcn_mfma_f32_16x16x32_bf16(kf[c], qf[1][c], sc[1][t], 0, 0, 0);
        }
      }
      if (kv0 + 63 > q0) {  // diagonal tiles only
#pragma unroll
        for (int u = 0; u < 2; ++u) {
          const int qrow = q0 + u * 16 + lo;
#pragma unroll
          for (int t = 0; t < 4; ++t)
#pragma unroll
            for (int j = 0; j < 4; ++j)
              if (kv0 + t * 16 + hi * 4 + j > qrow) sc[u][t][j] = -INFINITY;
        }
      }
#pragma unroll
      for (int u = 0; u < 2; ++u) {
        float tm = -INFINITY;
#pragma unroll
        for (int t = 0; t < 4; ++t)
#pragma unroll
          for (int j = 0; j < 4; ++j) tm = fmaxf(tm, sc[u][t][j]);
        tm = fmaxf(tm, __shfl_xor(tm, 16));
        tm = fmaxf(tm, __shfl_xor(tm, 32));
        const float nm = fmaxf(mrun[u], tm);
        const float corr = exp2f(mrun[u] - nm);
        mrun[u] = nm;
        float ps = 0.f;
        float p[4][4];
#pragma unroll
        for (int t = 0; t < 4; ++t)
#pragma unroll
          for (int j = 0; j < 4; ++j) { p[t][j] = exp2f(sc[u][t][j] - nm); ps += p[t][j]; }
        ps += __shfl_xor(ps, 16);
        ps += __shfl_xor(ps, 32);
        lrun[u] = lrun[u] * corr + ps;
#pragma unroll
        for (int c = 0; c < 10; ++c) acc[c][u] *= corr;
#pragma unroll
        for (int t = 0; t < 4; ++t) {
          s4v w = { (short)f2b(p[t][0]), (short)f2b(p[t][1]),
                    (short)f2b(p[t][2]), (short)f2b(p[t][3]) };
          *(s4v*)&Pl[wid][u][lo][t * 16 + hi * 4] = w;
        }
      }
      // re-fragment P: lane holds q=lo, kv = w*32 + hi*8 .. +7
      s8v pf[2][2];
#pragma unroll
      for (int u = 0; u < 2; ++u)
#pragma unroll
        for (int w = 0; w < 2; ++w)
          pf[u][w] = *(const s8v*)&Pl[wid][u][lo][w * 32 + hi * 8];
      // Y^T += V^T . P^T ; vf from swizzled Vs
#pragma unroll
      for (int c = 0; c < 10; ++c)
#pragma unroll
        for (int w = 0; w < 2; ++w) {
          const int slot = (w * 4 + hi) ^ (lo & 7);
          s8v vf = *(const s8v*)&Vc[((c * 16 + lo) * 8 + slot) * 8];
          acc[c][0] = __builtin_amdgcn_mfma_f32_16x16x32_bf16(vf, pf[0][w], acc[c][0], 0, 0, 0);
          acc[c][1] = __builtin_amdgcn_mfma_f32_16x16x32_bf16(vf, pf[1][w], acc[c][1], 0, 0, 0);
        }
    }
    cur ^= 1;
  }
#undef STAGEKV

  // epilogue: Y[b][t][h*148 + d] bf16, divide by l, skip pad d >= 148
  const int b = bh >> 3, h = bh & 7;
#pragma unroll
  for (int u = 0; u < 2; ++u) {
    const float inv = 1.0f / lrun[u];
    const int trow = q0 + u * 16 + lo;
    const size_t ybase = ((size_t)(b * T_ + trow)) * C_ + h * DK_;
#pragma unroll
    for (int c = 0; c < 10; ++c) {
      const int d0 = c * 16 + hi * 4;
      if (d0 + 3 < DK_) {
        s4v o = { (short)f2b(acc[c][u][0] * inv), (short)f2b(acc[c][u][1] * inv),
                  (short)f2b(acc[c][u][2] * inv), (short)f2b(acc[c][u][3] * inv) };
        *(s4v*)(Y + ybase + d0) = o;
      }
    }
  }
}

extern "C" void kernel_launch(void* const* d_in, const int* in_sizes, int n_in,
                              void* d_out, int out_size, void* d_ws, size_t ws_size,
                              hipStream_t stream) {
  const float* x  = (const float*)d_in[0];
  const float* wA = (const float*)d_in[1];
  const float* bA = (const float*)d_in[2];
  const float* wP = (const float*)d_in[3];
  const float* bP = (const float*)d_in[4];
  float* out = (float*)d_out;

  short* ws  = (short*)d_ws;
  short* xb  = ws;                  // [8192][1184] bf16; later reused as Y
  short* wab = xb + 9699328;        // [3584][1184]
  short* wpb = wab + 4243456;       // [1280][1184]
  short* Qb  = wpb + 1515520;       // [32][2048][160]
  short* Kb  = Qb + 10485760;       // [32][2048][160]
  short* Vt  = Kb + 10485760;       // [32][160][2048]

  cvt4<<<(9699328 / 4 + 255) / 256, 256, 0, stream>>>(x, xb, 9699328 / 4);
  cvt4<<<(4205568 / 4 + 255) / 256, 256, 0, stream>>>(wA, wab, 4205568 / 4);
  cvt4<<<(1401856 / 4 + 255) / 256, 256, 0, stream>>>(wP, wpb, 1401856 / 4);
  // zero Q,K so the d=148..159 contraction pad is exactly 0
  hipMemsetAsync(Qb, 0, (size_t)10485760 * 2, stream);
  hipMemsetAsync(Kb, 0, (size_t)10485760 * 2, stream);

  gemm_bt<0, 28><<<1792, 256, 0, stream>>>(xb, wab, bA, Qb, Kb, Vt, nullptr);
  attn<<<512, 256, 0, stream>>>(Qb, Kb, Vt, xb);  // Y aliases xb (dead)
  gemm_bt<1, 10><<<640, 256, 0, stream>>>(xb, wpb, bP, nullptr, nullptr, nullptr, out);
}